// Round 14
// baseline (522.954 us; speedup 1.0000x reference)
//
#include <hip/hip_runtime.h>
#include <hip/hip_bf16.h>

#define NTOK 8192
#define DMODEL 1024
#define NEXP 8
#define HID 2752
#define ALPHA 0.05f

#define BM 128
#define BN 128
#define BK 64
#define MAXTILES 72

typedef __attribute__((ext_vector_type(8))) short bf16x8;
typedef __attribute__((ext_vector_type(8))) unsigned short u16x8;
typedef __attribute__((ext_vector_type(4))) unsigned short u16x4;
typedef __attribute__((ext_vector_type(4))) float f32x4;

__device__ __forceinline__ unsigned short f2bf(float f){
  unsigned u = __builtin_bit_cast(unsigned, f);
  u += 0x7fffu + ((u >> 16) & 1u);   // RNE
  return (unsigned short)(u >> 16);
}

__device__ __forceinline__ void gload16(const void* g, void* l){
  __builtin_amdgcn_global_load_lds(
      (const __attribute__((address_space(1))) unsigned int*)g,
      (__attribute__((address_space(3))) unsigned int*)l, 16, 0, 0);
}

// ---------------- init ----------------
__global__ void k_init(int* counts, int* cursor, float* ce_sum){
  int t = threadIdx.x;
  if (t < NEXP){ counts[t] = 0; cursor[t] = 0; ce_sum[t] = 0.f; }
}

// ---------------- router (R6-verified: also emits x in bf16) ----------------
__global__ __launch_bounds__(1024) void k_router(
    const float* __restrict__ x, const float* __restrict__ Wg,
    const float* __restrict__ bg, int* __restrict__ counts,
    float* __restrict__ ce_sum, int* __restrict__ top1, float* __restrict__ gate,
    unsigned short* __restrict__ xb)
{
  __shared__ float wg[NEXP*DMODEL];
  __shared__ float ce_blk[NEXP];
  __shared__ int   cnt_blk[NEXP];
  const int tid = threadIdx.x;
  for (int i = tid; i < NEXP*DMODEL; i += 1024) wg[i] = Wg[i];
  if (tid < NEXP){ ce_blk[tid] = 0.f; cnt_blk[tid] = 0; }
  __syncthreads();
  const int wave = tid >> 6, lane = tid & 63;
  const int t = blockIdx.x * 16 + wave;
  float acc[NEXP];
  #pragma unroll
  for (int e = 0; e < NEXP; e++) acc[e] = 0.f;
  const float* xr = x + (size_t)t * DMODEL;
  unsigned short* xbr = xb + (size_t)t * DMODEL;
  #pragma unroll
  for (int kb = 0; kb < DMODEL; kb += 256){
    const float4 xv = *(const float4*)(xr + kb + lane*4);
    u16x4 o; o[0]=f2bf(xv.x); o[1]=f2bf(xv.y); o[2]=f2bf(xv.z); o[3]=f2bf(xv.w);
    *(u16x4*)(xbr + kb + lane*4) = o;
    #pragma unroll
    for (int e = 0; e < NEXP; e++){
      const float4 wv = *(const float4*)(wg + e*DMODEL + kb + lane*4);
      acc[e] += xv.x*wv.x + xv.y*wv.y + xv.z*wv.z + xv.w*wv.w;
    }
  }
  #pragma unroll
  for (int e = 0; e < NEXP; e++){
    float v = acc[e];
    #pragma unroll
    for (int off = 32; off; off >>= 1) v += __shfl_xor(v, off);
    acc[e] = v;
  }
  if (lane == 0){
    float mx = -1e30f; int bi = 0;
    float lg[NEXP];
    #pragma unroll
    for (int e = 0; e < NEXP; e++){
      lg[e] = acc[e] + bg[e];
      if (lg[e] > mx){ mx = lg[e]; bi = e; }
    }
    float s = 0.f, p[NEXP];
    #pragma unroll
    for (int e = 0; e < NEXP; e++){ p[e] = __expf(lg[e]-mx); s += p[e]; }
    const float inv = 1.f/s;
    #pragma unroll
    for (int e = 0; e < NEXP; e++) atomicAdd(&ce_blk[e], p[e]*inv);
    top1[t] = bi;
    gate[t] = p[bi]*inv;
    atomicAdd(&cnt_blk[bi], 1);
  }
  __syncthreads();
  if (tid < NEXP){
    atomicAdd(&counts[tid], cnt_blk[tid]);
    atomicAdd(&ce_sum[tid], ce_blk[tid]);
  }
}

// ---------------- f32 -> bf16, all three weight tensors ----------------
__global__ __launch_bounds__(256) void k_cvtw(
    const float* __restrict__ Wu, const float* __restrict__ Wv, const float* __restrict__ Wd,
    unsigned short* __restrict__ Wub, unsigned short* __restrict__ Wvb,
    unsigned short* __restrict__ Wdb, int w8)
{
  const int tot = 3*w8;
  for (size_t i = (size_t)blockIdx.x*256 + threadIdx.x; i < (size_t)tot; i += (size_t)2048*256){
    const float* s; unsigned short* d; size_t j;
    if (i < (size_t)w8)        { s = Wu; d = Wub; j = i; }
    else if (i < (size_t)2*w8) { s = Wv; d = Wvb; j = i - w8; }
    else                       { s = Wd; d = Wdb; j = i - 2*(size_t)w8; }
    const float4 a = ((const float4*)s)[j*2];
    const float4 b = ((const float4*)s)[j*2+1];
    u16x8 o;
    o[0]=f2bf(a.x); o[1]=f2bf(a.y); o[2]=f2bf(a.z); o[3]=f2bf(a.w);
    o[4]=f2bf(b.x); o[5]=f2bf(b.y); o[6]=f2bf(b.z); o[7]=f2bf(b.w);
    ((u16x8*)d)[j] = o;
  }
}

// ---------------- scan ----------------
__global__ void k_scan(const int* __restrict__ counts, const float* __restrict__ ce_sum,
                       int* offsets, int* nTiles, int* tileE, int* tileBase, int* tileCnt,
                       float* aux_out)
{
  if (threadIdx.x == 0){
    int off = 0;
    for (int e = 0; e < NEXP; e++){ offsets[e] = off; off += counts[e]; }
    offsets[NEXP] = off;
    int nt = 0;
    for (int e = 0; e < NEXP; e++){
      for (int r = 0; r < counts[e]; r += BM){
        tileE[nt] = e;
        tileBase[nt] = offsets[e] + r;
        int rem = counts[e] - r;
        tileCnt[nt] = rem < BM ? rem : BM;
        nt++;
      }
    }
    *nTiles = nt;
    float aux = 0.f;
    for (int e = 0; e < NEXP; e++)
      aux += ((float)counts[e] / (float)NTOK) * (ce_sum[e] / (float)NTOK);
    aux_out[0] = ALPHA * (float)NEXP * aux;
  }
}

// ---------------- scatter ----------------
__global__ __launch_bounds__(256) void k_scatter(const int* __restrict__ top1,
                                                 int* cursor, const int* __restrict__ offsets,
                                                 int* __restrict__ perm)
{
  const int t = blockIdx.x*256 + threadIdx.x;
  const int e = top1[t];
  const int lane = threadIdx.x & 63;
  int slot = 0;
  #pragma unroll
  for (int ee = 0; ee < NEXP; ee++){
    unsigned long long mask = __ballot(e == ee);
    if (e == ee){
      int leader = __ffsll(mask) - 1;
      int nbelow = __popcll(mask & ((1ull << lane) - 1ull));
      int base = 0;
      if (lane == leader) base = atomicAdd(&cursor[ee], __popcll(mask));
      base = __shfl(base, leader);
      slot = offsets[ee] + base + nbelow;
    }
  }
  perm[slot] = t;
}

// ============ grouped GEMMs: A via LDS (verified path), B via registers ============
// LDS-BW relief: per-wave ds_reads drop 24->8 per K-step; B fragments loaded
// directly global->VGPR (bf16x8; per-lane row = output col, fq = K-slice).
// A swizzle seg^=(row&7) and gload lane-linear dest unchanged (R5-verified).

__global__ __launch_bounds__(256,2) void k_up16(
    const unsigned short* __restrict__ xb,
    const unsigned short* __restrict__ Wub, const unsigned short* __restrict__ Wvb,
    const int* __restrict__ perm,
    const int* __restrict__ nTiles, const int* __restrict__ tileE,
    const int* __restrict__ tileBase, const int* __restrict__ tileCnt,
    unsigned short* __restrict__ h)
{
  // XCD-chunked: grid 1584 = 8 XCDs x 198
  const int l     = ((int)blockIdx.x % 8) * 198 + (int)blockIdx.x / 8;
  const int tileI = l % 72;
  const int ncol0 = (l / 72) * BN;
  if (tileI >= *nTiles) return;
  const int e    = tileE[tileI];
  const int base = tileBase[tileI];
  const int cnt  = tileCnt[tileI];

  __shared__ __align__(16) unsigned short As[BM*BK];   // 16KB, A only

  const int tid = threadIdx.x;
  const int wv = tid >> 6, ln = tid & 63;

  // A staging sources (4 chunks of 8 rows per wave), inverse-swizzled
  const unsigned short* srcA[4];
  #pragma unroll
  for (int c = 0; c < 4; c++){
    const int r  = wv*32 + c*8 + (ln>>3);
    const int sp = (ln&7) ^ (r&7);
    const int ra = (r < cnt) ? r : (cnt-1);
    srcA[c] = xb + (size_t)perm[base + ra]*DMODEL + sp*8;
  }

  const int wm = (wv >> 1) * 64, wn = (wv & 1) * 64;
  const int fr = ln & 15, fq = ln >> 4;

  // B register-load base pointers (per lane; only K-offset varies in-loop)
  const unsigned short* bU[4];
  const unsigned short* bV[4];
  #pragma unroll
  for (int n = 0; n < 4; n++){
    int rb = ncol0 + wn + n*16 + fr; if (rb >= HID) rb = HID-1;  // masked at write
    bU[n] = Wub + ((size_t)e*HID + rb)*DMODEL + fq*8;
    bV[n] = Wvb + ((size_t)e*HID + rb)*DMODEL + fq*8;
  }

  f32x4 accU[4][4], accV[4][4];
  #pragma unroll
  for (int m = 0; m < 4; m++)
    #pragma unroll
    for (int n = 0; n < 4; n++)
      #pragma unroll
      for (int j = 0; j < 4; j++){ accU[m][n][j] = 0.f; accV[m][n][j] = 0.f; }

  for (int kb = 0; kb < DMODEL; kb += BK){
    #pragma unroll
    for (int c = 0; c < 4; c++)
      gload16(srcA[c] + kb, (char*)As + wv*4096 + c*1024);
    __syncthreads();
    #pragma unroll
    for (int ks = 0; ks < 2; ks++){
      bf16x8 bu[4], bv[4], af[4];
      #pragma unroll
      for (int n = 0; n < 4; n++){            // global loads first (longest latency)
        bu[n] = *(const bf16x8*)(bU[n] + kb + ks*32);
        bv[n] = *(const bf16x8*)(bV[n] + kb + ks*32);
      }
      #pragma unroll
      for (int m = 0; m < 4; m++){
        int r = wm + m*16 + fr;
        af[m] = *(const bf16x8*)((const char*)As + r*128 + ((ks*64 + fq*16) ^ ((r&7)<<4)));
      }
      #pragma unroll
      for (int m = 0; m < 4; m++)
        #pragma unroll
        for (int n = 0; n < 4; n++){
          accU[m][n] = __builtin_amdgcn_mfma_f32_16x16x32_bf16(af[m], bu[n], accU[m][n], 0,0,0);
          accV[m][n] = __builtin_amdgcn_mfma_f32_16x16x32_bf16(af[m], bv[n], accV[m][n], 0,0,0);
        }
    }
    __syncthreads();
  }
  #pragma unroll
  for (int m = 0; m < 4; m++)
    #pragma unroll
    for (int n = 0; n < 4; n++)
      #pragma unroll
      for (int j = 0; j < 4; j++){
        int r = wm + m*16 + fq*4 + j;
        int c = ncol0 + wn + n*16 + fr;
        if (r < cnt && c < HID){
          float u = accU[m][n][j], v = accV[m][n][j];
          float hv = (u / (1.f + __expf(-u))) * v;
          h[(size_t)(base + r)*HID + c] = f2bf(hv);
        }
      }
}

__global__ __launch_bounds__(256,2) void k_down16(
    const unsigned short* __restrict__ h, const unsigned short* __restrict__ Wdb,
    const int* __restrict__ perm, const float* __restrict__ gate,
    const int* __restrict__ nTiles, const int* __restrict__ tileE,
    const int* __restrict__ tileBase, const int* __restrict__ tileCnt,
    float* __restrict__ out)
{
  const int l     = ((int)blockIdx.x % 8) * 72 + (int)blockIdx.x / 8;
  const int tileI = l % 72;
  const int ncol0 = (l / 72) * BN;
  if (tileI >= *nTiles) return;
  const int e    = tileE[tileI];
  const int base = tileBase[tileI];
  const int cnt  = tileCnt[tileI];

  __shared__ __align__(16) unsigned short As[BM*BK];   // 16KB, A only
  __shared__ int   tokL[BM];
  __shared__ float gateL[BM];

  const int tid = threadIdx.x;
  if (tid < BM){
    int rr = (tid < cnt) ? tid : 0;
    int tk = perm[base + rr];
    tokL[tid] = tk;
    gateL[tid] = gate[tk];
  }
  const int wv = tid >> 6, ln = tid & 63;

  const unsigned short* srcA[4];
  #pragma unroll
  for (int c = 0; c < 4; c++){
    const int r  = wv*32 + c*8 + (ln>>3);
    const int sp = (ln&7) ^ (r&7);
    const int ra = (r < cnt) ? r : (cnt-1);
    srcA[c] = h + (size_t)(base + ra)*HID + sp*8;
  }

  const int wm = (wv >> 1) * 64, wn = (wv & 1) * 64;
  const int fr = ln & 15, fq = ln >> 4;

  const unsigned short* bD[4];
  #pragma unroll
  for (int n = 0; n < 4; n++){
    const int rb = ncol0 + wn + n*16 + fr;     // < 1024 always
    bD[n] = Wdb + ((size_t)e*DMODEL + rb)*HID + fq*8;
  }

  f32x4 acc[4][4];
  #pragma unroll
  for (int m = 0; m < 4; m++)
    #pragma unroll
    for (int n = 0; n < 4; n++)
      #pragma unroll
      for (int j = 0; j < 4; j++) acc[m][n][j] = 0.f;

  for (int kb = 0; kb < HID; kb += BK){   // 43 iters
    #pragma unroll
    for (int c = 0; c < 4; c++)
      gload16(srcA[c] + kb, (char*)As + wv*4096 + c*1024);
    __syncthreads();
    #pragma unroll
    for (int ks = 0; ks < 2; ks++){
      bf16x8 bf[4], af[4];
      #pragma unroll
      for (int n = 0; n < 4; n++)
        bf[n] = *(const bf16x8*)(bD[n] + kb + ks*32);
      #pragma unroll
      for (int m = 0; m < 4; m++){
        int r = wm + m*16 + fr;
        af[m] = *(const bf16x8*)((const char*)As + r*128 + ((ks*64 + fq*16) ^ ((r&7)<<4)));
      }
      #pragma unroll
      for (int m = 0; m < 4; m++)
        #pragma unroll
        for (int n = 0; n < 4; n++)
          acc[m][n] = __builtin_amdgcn_mfma_f32_16x16x32_bf16(af[m], bf[n], acc[m][n], 0,0,0);
    }
    __syncthreads();
  }
  #pragma unroll
  for (int m = 0; m < 4; m++)
    #pragma unroll
    for (int n = 0; n < 4; n++)
      #pragma unroll
      for (int j = 0; j < 4; j++){
        int r = wm + m*16 + fq*4 + j;
        int c = ncol0 + wn + n*16 + fr;
        if (r < cnt)
          out[(size_t)tokL[r]*DMODEL + c] = acc[m][n][j] * gateL[r];
      }
}

// ---------------- launch ----------------
extern "C" void kernel_launch(void* const* d_in, const int* in_sizes, int n_in,
                              void* d_out, int out_size, void* d_ws, size_t ws_size,
                              hipStream_t stream)
{
  const float* x  = (const float*)d_in[0];
  const float* Wg = (const float*)d_in[1];
  const float* bg = (const float*)d_in[2];
  const float* Wu = (const float*)d_in[3];
  const float* Wv = (const float*)d_in[4];
  const float* Wd = (const float*)d_in[5];
  float* out = (float*)d_out;

  char* ws = (char*)d_ws;
  int*   counts   = (int*)(ws + 0);
  int*   cursor   = (int*)(ws + 32);
  int*   offsets  = (int*)(ws + 64);
  float* ce_sum   = (float*)(ws + 128);
  int*   nTiles   = (int*)(ws + 192);
  int*   tileE    = (int*)(ws + 256);
  int*   tileBase = (int*)(ws + 768);
  int*   tileCnt  = (int*)(ws + 1280);
  int*   top1     = (int*)(ws + 2048);
  float* gate     = (float*)(ws + 34816);
  int*   perm     = (int*)(ws + 67584);
  unsigned short* xb   = (unsigned short*)(ws + 100352);
  unsigned short* hbuf = (unsigned short*)(ws + 100352 + (size_t)NTOK*DMODEL*2);
  const size_t W_ELEMS = (size_t)NEXP*HID*DMODEL;           // 22,544,384
  const size_t baseW = 100352 + (size_t)NTOK*DMODEL*2 + (size_t)NTOK*HID*2;
  unsigned short* Wub = (unsigned short*)(ws + baseW);
  unsigned short* Wvb = (unsigned short*)(ws + baseW + W_ELEMS*2);
  unsigned short* Wdb = (unsigned short*)(ws + baseW + W_ELEMS*4);

  k_init<<<1, 64, 0, stream>>>(counts, cursor, ce_sum);
  k_router<<<NTOK/16, 1024, 0, stream>>>(x, Wg, bg, counts, ce_sum, top1, gate, xb);
  k_scan<<<1, 64, 0, stream>>>(counts, ce_sum, offsets, nTiles, tileE, tileBase, tileCnt,
                               out + (size_t)NTOK*DMODEL);
  k_scatter<<<NTOK/256, 256, 0, stream>>>(top1, cursor, offsets, perm);
  k_cvtw<<<2048, 256, 0, stream>>>(Wu, Wv, Wd, Wub, Wvb, Wdb, (int)(W_ELEMS/8));

  k_up16<<<MAXTILES*((HID + BN - 1)/BN), 256, 0, stream>>>(
      xb, Wub, Wvb, perm, nTiles, tileE, tileBase, tileCnt, hbuf);
  k_down16<<<MAXTILES*(DMODEL/BN), 256, 0, stream>>>(
      hbuf, Wdb, perm, gate, nTiles, tileE, tileBase, tileCnt, out);
}

// Round 15
// 341.792 us; speedup vs baseline: 1.5300x; 1.5300x over previous
//
#include <hip/hip_runtime.h>
#include <hip/hip_bf16.h>

#define NTOK 8192
#define DMODEL 1024
#define NEXP 8
#define HID 2752
#define ALPHA 0.05f

#define BM 128
#define BN 128
#define BK 64
#define MAXTILES 72

typedef __attribute__((ext_vector_type(8))) short bf16x8;
typedef __attribute__((ext_vector_type(8))) unsigned short u16x8;
typedef __attribute__((ext_vector_type(4))) unsigned short u16x4;
typedef __attribute__((ext_vector_type(4))) float f32x4;

__device__ __forceinline__ unsigned short f2bf(float f){
  unsigned u = __builtin_bit_cast(unsigned, f);
  u += 0x7fffu + ((u >> 16) & 1u);   // RNE
  return (unsigned short)(u >> 16);
}

__device__ __forceinline__ void gload16(const void* g, void* l){
  __builtin_amdgcn_global_load_lds(
      (const __attribute__((address_space(1))) unsigned int*)g,
      (__attribute__((address_space(3))) unsigned int*)l, 16, 0, 0);
}

// ---------------- init ----------------
__global__ void k_init(int* counts, int* cursor, float* ce_sum){
  int t = threadIdx.x;
  if (t < NEXP){ counts[t] = 0; cursor[t] = 0; ce_sum[t] = 0.f; }
}

// ---------------- router (also emits x in bf16) ----------------
__global__ __launch_bounds__(1024) void k_router(
    const float* __restrict__ x, const float* __restrict__ Wg,
    const float* __restrict__ bg, int* __restrict__ counts,
    float* __restrict__ ce_sum, int* __restrict__ top1, float* __restrict__ gate,
    unsigned short* __restrict__ xb)
{
  __shared__ float wg[NEXP*DMODEL];
  __shared__ float ce_blk[NEXP];
  __shared__ int   cnt_blk[NEXP];
  const int tid = threadIdx.x;
  for (int i = tid; i < NEXP*DMODEL; i += 1024) wg[i] = Wg[i];
  if (tid < NEXP){ ce_blk[tid] = 0.f; cnt_blk[tid] = 0; }
  __syncthreads();
  const int wave = tid >> 6, lane = tid & 63;
  const int t = blockIdx.x * 16 + wave;
  float acc[NEXP];
  #pragma unroll
  for (int e = 0; e < NEXP; e++) acc[e] = 0.f;
  const float* xr = x + (size_t)t * DMODEL;
  unsigned short* xbr = xb + (size_t)t * DMODEL;
  #pragma unroll
  for (int kb = 0; kb < DMODEL; kb += 256){
    const float4 xv = *(const float4*)(xr + kb + lane*4);
    u16x4 o; o[0]=f2bf(xv.x); o[1]=f2bf(xv.y); o[2]=f2bf(xv.z); o[3]=f2bf(xv.w);
    *(u16x4*)(xbr + kb + lane*4) = o;
    #pragma unroll
    for (int e = 0; e < NEXP; e++){
      const float4 wv = *(const float4*)(wg + e*DMODEL + kb + lane*4);
      acc[e] += xv.x*wv.x + xv.y*wv.y + xv.z*wv.z + xv.w*wv.w;
    }
  }
  #pragma unroll
  for (int e = 0; e < NEXP; e++){
    float v = acc[e];
    #pragma unroll
    for (int off = 32; off; off >>= 1) v += __shfl_xor(v, off);
    acc[e] = v;
  }
  if (lane == 0){
    float mx = -1e30f; int bi = 0;
    float lg[NEXP];
    #pragma unroll
    for (int e = 0; e < NEXP; e++){
      lg[e] = acc[e] + bg[e];
      if (lg[e] > mx){ mx = lg[e]; bi = e; }
    }
    float s = 0.f, p[NEXP];
    #pragma unroll
    for (int e = 0; e < NEXP; e++){ p[e] = __expf(lg[e]-mx); s += p[e]; }
    const float inv = 1.f/s;
    #pragma unroll
    for (int e = 0; e < NEXP; e++) atomicAdd(&ce_blk[e], p[e]*inv);
    top1[t] = bi;
    gate[t] = p[bi]*inv;
    atomicAdd(&cnt_blk[bi], 1);
  }
  __syncthreads();
  if (tid < NEXP){
    atomicAdd(&counts[tid], cnt_blk[tid]);
    atomicAdd(&ce_sum[tid], ce_blk[tid]);
  }
}

// ---------------- f32 -> bf16, all three weight tensors in one launch ----------------
__global__ __launch_bounds__(256) void k_cvtw(
    const float* __restrict__ Wu, const float* __restrict__ Wv, const float* __restrict__ Wd,
    unsigned short* __restrict__ Wub, unsigned short* __restrict__ Wvb,
    unsigned short* __restrict__ Wdb, int w8)
{
  const int tot = 3*w8;
  for (size_t i = (size_t)blockIdx.x*256 + threadIdx.x; i < (size_t)tot; i += (size_t)2048*256){
    const float* s; unsigned short* d; size_t j;
    if (i < (size_t)w8)        { s = Wu; d = Wub; j = i; }
    else if (i < (size_t)2*w8) { s = Wv; d = Wvb; j = i - w8; }
    else                       { s = Wd; d = Wdb; j = i - 2*(size_t)w8; }
    const float4 a = ((const float4*)s)[j*2];
    const float4 b = ((const float4*)s)[j*2+1];
    u16x8 o;
    o[0]=f2bf(a.x); o[1]=f2bf(a.y); o[2]=f2bf(a.z); o[3]=f2bf(a.w);
    o[4]=f2bf(b.x); o[5]=f2bf(b.y); o[6]=f2bf(b.z); o[7]=f2bf(b.w);
    ((u16x8*)d)[j] = o;
  }
}

// ---------------- scan ----------------
__global__ void k_scan(const int* __restrict__ counts, const float* __restrict__ ce_sum,
                       int* offsets, int* nTiles, int* tileE, int* tileBase, int* tileCnt,
                       float* aux_out)
{
  if (threadIdx.x == 0){
    int off = 0;
    for (int e = 0; e < NEXP; e++){ offsets[e] = off; off += counts[e]; }
    offsets[NEXP] = off;
    int nt = 0;
    for (int e = 0; e < NEXP; e++){
      for (int r = 0; r < counts[e]; r += BM){
        tileE[nt] = e;
        tileBase[nt] = offsets[e] + r;
        int rem = counts[e] - r;
        tileCnt[nt] = rem < BM ? rem : BM;
        nt++;
      }
    }
    *nTiles = nt;
    float aux = 0.f;
    for (int e = 0; e < NEXP; e++)
      aux += ((float)counts[e] / (float)NTOK) * (ce_sum[e] / (float)NTOK);
    aux_out[0] = ALPHA * (float)NEXP * aux;
  }
}

// ---------------- scatter ----------------
__global__ __launch_bounds__(256) void k_scatter(const int* __restrict__ top1,
                                                 int* cursor, const int* __restrict__ offsets,
                                                 int* __restrict__ perm)
{
  const int t = blockIdx.x*256 + threadIdx.x;
  const int e = top1[t];
  const int lane = threadIdx.x & 63;
  int slot = 0;
  #pragma unroll
  for (int ee = 0; ee < NEXP; ee++){
    unsigned long long mask = __ballot(e == ee);
    if (e == ee){
      int leader = __ffsll(mask) - 1;
      int nbelow = __popcll(mask & ((1ull << lane) - 1ull));
      int base = 0;
      if (lane == leader) base = atomicAdd(&cursor[ee], __popcll(mask));
      base = __shfl(base, leader);
      slot = offsets[ee] + base + nbelow;
    }
  }
  perm[slot] = t;
}

// ============ k_up16: BK=32, depth-2 pipeline with counted vmcnt (R6-verified, 159us) ============
#define STG(AB, BB, CB, ofs) { \
  gload16(srcA[0]+(ofs), (char*)(AB) + ldo); \
  gload16(srcA[1]+(ofs), (char*)(AB) + 4096 + ldo); \
  gload16(srcU[0]+(ofs), (char*)(BB) + ldo); \
  gload16(srcU[1]+(ofs), (char*)(BB) + 4096 + ldo); \
  gload16(srcV[0]+(ofs), (char*)(CB) + ldo); \
  gload16(srcV[1]+(ofs), (char*)(CB) + 4096 + ldo); }

__global__ __launch_bounds__(256,2) void k_up16(
    const unsigned short* __restrict__ xb,
    const unsigned short* __restrict__ Wub, const unsigned short* __restrict__ Wvb,
    const int* __restrict__ perm,
    const int* __restrict__ nTiles, const int* __restrict__ tileE,
    const int* __restrict__ tileBase, const int* __restrict__ tileCnt,
    unsigned short* __restrict__ h)
{
  const int l     = ((int)blockIdx.x % 8) * 198 + (int)blockIdx.x / 8;
  const int tileI = l % 72;
  const int ncol0 = (l / 72) * BN;
  if (tileI >= *nTiles) return;          // block-uniform: before any barrier
  const int e    = tileE[tileI];
  const int base = tileBase[tileI];
  const int cnt  = tileCnt[tileI];

  __shared__ __align__(16) unsigned short As [2][BM*32];
  __shared__ __align__(16) unsigned short Bus[2][BM*32];
  __shared__ __align__(16) unsigned short Bvs[2][BM*32];

  const int tid = threadIdx.x;
  const int wv = tid >> 6, ln = tid & 63;

  const unsigned short* srcA[2];
  const unsigned short* srcU[2];
  const unsigned short* srcV[2];
  #pragma unroll
  for (int c = 0; c < 2; c++){
    const int r  = c*64 + wv*16 + (ln>>2);
    const int sp = (ln&3) ^ ((r>>1)&3);
    const int ra = (r < cnt) ? r : (cnt-1);
    srcA[c] = xb + (size_t)perm[base + ra]*DMODEL + sp*8;
    int rb = ncol0 + r; if (rb >= HID) rb = HID-1;
    srcU[c] = Wub + ((size_t)e*HID + rb)*DMODEL + sp*8;
    srcV[c] = Wvb + ((size_t)e*HID + rb)*DMODEL + sp*8;
  }
  const unsigned ldo = wv*1024;

  const int wm = (wv >> 1) * 64, wn = (wv & 1) * 64;
  const int fr = ln & 15, fq = ln >> 4;

  f32x4 accU[4][4], accV[4][4];
  #pragma unroll
  for (int m = 0; m < 4; m++)
    #pragma unroll
    for (int n = 0; n < 4; n++)
      #pragma unroll
      for (int j = 0; j < 4; j++){ accU[m][n][j] = 0.f; accV[m][n][j] = 0.f; }

  STG(As[0], Bus[0], Bvs[0], 0);
  STG(As[1], Bus[1], Bvs[1], 32);
  asm volatile("s_waitcnt vmcnt(6)" ::: "memory");
  __builtin_amdgcn_s_barrier();

  #pragma unroll 2
  for (int t = 0; t < 32; ++t){
    const int bb = t & 1;
    bf16x8 af[4], bu[4], bv[4];
    #pragma unroll
    for (int m = 0; m < 4; m++){
      int r = wm + m*16 + fr;
      int off = r*64 + ((fq ^ ((r>>1)&3))<<4);
      af[m] = *(const bf16x8*)((const char*)As[bb] + off);
    }
    #pragma unroll
    for (int n = 0; n < 4; n++){
      int r = wn + n*16 + fr;
      int off = r*64 + ((fq ^ ((r>>1)&3))<<4);
      bu[n] = *(const bf16x8*)((const char*)Bus[bb] + off);
      bv[n] = *(const bf16x8*)((const char*)Bvs[bb] + off);
    }
    asm volatile("s_waitcnt lgkmcnt(0)" ::: "memory");
    __builtin_amdgcn_sched_barrier(0);
    __builtin_amdgcn_s_barrier();
    if (t < 30) STG(As[bb], Bus[bb], Bvs[bb], (t+2)*32);
    __builtin_amdgcn_s_setprio(1);
    #pragma unroll
    for (int m = 0; m < 4; m++)
      #pragma unroll
      for (int n = 0; n < 4; n++){
        accU[m][n] = __builtin_amdgcn_mfma_f32_16x16x32_bf16(af[m], bu[n], accU[m][n], 0,0,0);
        accV[m][n] = __builtin_amdgcn_mfma_f32_16x16x32_bf16(af[m], bv[n], accV[m][n], 0,0,0);
      }
    __builtin_amdgcn_s_setprio(0);
    if (t < 30)       { asm volatile("s_waitcnt vmcnt(6)" ::: "memory"); }
    else if (t == 30) { asm volatile("s_waitcnt vmcnt(0)" ::: "memory"); }
    if (t < 31) __builtin_amdgcn_s_barrier();
  }

  #pragma unroll
  for (int m = 0; m < 4; m++)
    #pragma unroll
    for (int n = 0; n < 4; n++)
      #pragma unroll
      for (int j = 0; j < 4; j++){
        int r = wm + m*16 + fq*4 + j;
        int c = ncol0 + wn + n*16 + fr;
        if (r < cnt && c < HID){
          float u = accU[m][n][j], v = accV[m][n][j];
          float hv = (u / (1.f + __expf(-u))) * v;
          h[(size_t)(base + r)*HID + c] = f2bf(hv);
        }
      }
}

// ---------------- k_down16: R5-verified BK=64 core + XCD-chunked grid ----------------
__global__ __launch_bounds__(256,2) void k_down16(
    const unsigned short* __restrict__ h, const unsigned short* __restrict__ Wdb,
    const int* __restrict__ perm, const float* __restrict__ gate,
    const int* __restrict__ nTiles, const int* __restrict__ tileE,
    const int* __restrict__ tileBase, const int* __restrict__ tileCnt,
    float* __restrict__ out)
{
  const int l     = ((int)blockIdx.x % 8) * 72 + (int)blockIdx.x / 8;
  const int tileI = l % 72;
  const int ncol0 = (l / 72) * BN;
  if (tileI >= *nTiles) return;
  const int e    = tileE[tileI];
  const int base = tileBase[tileI];
  const int cnt  = tileCnt[tileI];

  __shared__ __align__(16) unsigned short As[BM*BK];
  __shared__ __align__(16) unsigned short Bs[BM*BK];
  __shared__ int   tokL[BM];
  __shared__ float gateL[BM];

  const int tid = threadIdx.x;
  if (tid < BM){
    int rr = (tid < cnt) ? tid : 0;
    int tk = perm[base + rr];
    tokL[tid] = tk;
    gateL[tid] = gate[tk];
  }
  const int wv = tid >> 6, ln = tid & 63;

  const unsigned short* srcA[4];
  const unsigned short* srcB[4];
  #pragma unroll
  for (int c = 0; c < 4; c++){
    const int r  = wv*32 + c*8 + (ln>>3);
    const int sp = (ln&7) ^ (r&7);
    const int ra = (r < cnt) ? r : (cnt-1);
    srcA[c] = h + (size_t)(base + ra)*HID + sp*8;
    const int rb = ncol0 + r;
    srcB[c] = Wdb + ((size_t)e*DMODEL + rb)*HID + sp*8;
  }

  const int wm = (wv >> 1) * 64, wn = (wv & 1) * 64;
  const int fr = ln & 15, fq = ln >> 4;

  f32x4 acc[4][4];
  #pragma unroll
  for (int m = 0; m < 4; m++)
    #pragma unroll
    for (int n = 0; n < 4; n++)
      #pragma unroll
      for (int j = 0; j < 4; j++) acc[m][n][j] = 0.f;

  for (int kb = 0; kb < HID; kb += BK){   // 43 iters
    #pragma unroll
    for (int c = 0; c < 4; c++){
      const unsigned ldo = wv*4096 + c*1024;
      gload16(srcA[c] + kb, (char*)As + ldo);
      gload16(srcB[c] + kb, (char*)Bs + ldo);
    }
    __syncthreads();
    #pragma unroll
    for (int ks = 0; ks < 2; ks++){
      bf16x8 af[4], bf[4];
      #pragma unroll
      for (int m = 0; m < 4; m++){
        int r = wm + m*16 + fr;
        af[m] = *(const bf16x8*)((const char*)As + r*128 + ((ks*64 + fq*16) ^ ((r&7)<<4)));
      }
      #pragma unroll
      for (int n = 0; n < 4; n++){
        int r = wn + n*16 + fr;
        bf[n] = *(const bf16x8*)((const char*)Bs + r*128 + ((ks*64 + fq*16) ^ ((r&7)<<4)));
      }
      #pragma unroll
      for (int m = 0; m < 4; m++)
        #pragma unroll
        for (int n = 0; n < 4; n++)
          acc[m][n] = __builtin_amdgcn_mfma_f32_16x16x32_bf16(af[m], bf[n], acc[m][n], 0,0,0);
    }
    __syncthreads();
  }
  #pragma unroll
  for (int m = 0; m < 4; m++)
    #pragma unroll
    for (int n = 0; n < 4; n++)
      #pragma unroll
      for (int j = 0; j < 4; j++){
        int r = wm + m*16 + fq*4 + j;
        int c = ncol0 + wn + n*16 + fr;
        if (r < cnt)
          out[(size_t)tokL[r]*DMODEL + c] = acc[m][n][j] * gateL[r];
      }
}

// ---------------- launch ----------------
extern "C" void kernel_launch(void* const* d_in, const int* in_sizes, int n_in,
                              void* d_out, int out_size, void* d_ws, size_t ws_size,
                              hipStream_t stream)
{
  const float* x  = (const float*)d_in[0];
  const float* Wg = (const float*)d_in[1];
  const float* bg = (const float*)d_in[2];
  const float* Wu = (const float*)d_in[3];
  const float* Wv = (const float*)d_in[4];
  const float* Wd = (const float*)d_in[5];
  float* out = (float*)d_out;

  char* ws = (char*)d_ws;
  int*   counts   = (int*)(ws + 0);
  int*   cursor   = (int*)(ws + 32);
  int*   offsets  = (int*)(ws + 64);
  float* ce_sum   = (float*)(ws + 128);
  int*   nTiles   = (int*)(ws + 192);
  int*   tileE    = (int*)(ws + 256);
  int*   tileBase = (int*)(ws + 768);
  int*   tileCnt  = (int*)(ws + 1280);
  int*   top1     = (int*)(ws + 2048);
  float* gate     = (float*)(ws + 34816);
  int*   perm     = (int*)(ws + 67584);
  unsigned short* xb   = (unsigned short*)(ws + 100352);
  unsigned short* hbuf = (unsigned short*)(ws + 100352 + (size_t)NTOK*DMODEL*2);
  const size_t W_ELEMS = (size_t)NEXP*HID*DMODEL;           // 22,544,384
  const size_t baseW = 100352 + (size_t)NTOK*DMODEL*2 + (size_t)NTOK*HID*2;
  unsigned short* Wub = (unsigned short*)(ws + baseW);
  unsigned short* Wvb = (unsigned short*)(ws + baseW + W_ELEMS*2);
  unsigned short* Wdb = (unsigned short*)(ws + baseW + W_ELEMS*4);

  k_init<<<1, 64, 0, stream>>>(counts, cursor, ce_sum);
  k_router<<<NTOK/16, 1024, 0, stream>>>(x, Wg, bg, counts, ce_sum, top1, gate, xb);
  k_scan<<<1, 64, 0, stream>>>(counts, ce_sum, offsets, nTiles, tileE, tileBase, tileCnt,
                               out + (size_t)NTOK*DMODEL);
  k_scatter<<<NTOK/256, 256, 0, stream>>>(top1, cursor, offsets, perm);
  k_cvtw<<<2048, 256, 0, stream>>>(Wu, Wv, Wd, Wub, Wvb, Wdb, (int)(W_ELEMS/8));

  k_up16<<<MAXTILES*((HID + BN - 1)/BN), 256, 0, stream>>>(
      xb, Wub, Wvb, perm, nTiles, tileE, tileBase, tileCnt, hbuf);
  k_down16<<<MAXTILES*(DMODEL/BN), 256, 0, stream>>>(
      hbuf, Wdb, perm, gate, nTiles, tileE, tileBase, tileCnt, out);
}